// Round 3
// baseline (39.126 us; speedup 1.0000x reference)
//
#include <hip/hip_runtime.h>
#include <hip/hip_fp16.h>

// out[m][n] = fp16( fp16( (sum_k x[m][k]*w6[n][k]) * scale[n] ) + bias[n] ), stored fp32
// Harness pushes all fp16 reference tensors upcast to fp32:
//   x: fp32 [256][4096] (fp16-exact values), w6: fp32 [4096][4096] (e3m2 grid, fp16-exact),
//   scales/bias: fp32 [4096] (fp16-exact), out: fp32 [256][4096]
// => convert to fp16 (exact), f16 MFMA, fp32 accumulate.

typedef __attribute__((ext_vector_type(8))) _Float16 half8;  // one MFMA A/B frag (4 VGPRs)
typedef __attribute__((ext_vector_type(4))) float f32x4;     // MFMA accumulator frag

constexpr int K  = 4096;
constexpr int N  = 4096;
constexpr int BM = 64;
constexpr int BN = 64;
constexpr int BK = 64;
constexpr int LDH = BK + 8;   // LDS row stride in halves: 144 B (16B-aligned, bank-spread)

__device__ __forceinline__ half8 cvt8(float4 a, float4 b) {
    half8 h;
    h[0] = (_Float16)a.x; h[1] = (_Float16)a.y; h[2] = (_Float16)a.z; h[3] = (_Float16)a.w;
    h[4] = (_Float16)b.x; h[5] = (_Float16)b.y; h[6] = (_Float16)b.z; h[7] = (_Float16)b.w;
    return h;
}

__global__ __launch_bounds__(512)
void fp6lin_kernel(const float* __restrict__ X,
                   const float* __restrict__ W,
                   const float* __restrict__ S,
                   const float* __restrict__ Bi,
                   float* __restrict__ O)
{
    __shared__ _Float16 lw[BN * LDH];   // W tile as fp16: [64][72]
    __shared__ _Float16 lx[BM * LDH];   // x tile as fp16: [64][72]

    const int tid  = (int)threadIdx.x;
    const int lane = tid & 63;
    const int wid  = tid >> 6;          // 8 waves: 2 (M) x 4 (N)
    const int wm   = (wid & 1) * 32;    // wave tile 32 rows
    const int wn   = (wid >> 1) * 16;   // x 16 cols

    // XCD swizzle: 256 blocks / 8 XCDs; the 4 M-tiles sharing a W panel are adjacent
    // in swz on the same XCD -> W streamed from HBM once, 3 L2 hits.
    const int bid = (int)blockIdx.x;
    const int swz = (bid & 7) * 32 + (bid >> 3);
    const int bm  = (swz & 3) * BM;     // 4 M-tiles
    const int bn  = (swz >> 2) * BN;    // 64 N-tiles

    // staging map: thread t loads row t>>3 (0..63), cols (t&7)*8 .. +8 of the K-slab
    const int srow = tid >> 3;
    const int scol = (tid & 7) * 8;
    const float* wp = W + (size_t)(bn + srow) * K + scol;
    const float* xp = X + (size_t)(bm + srow) * K + scol;
    _Float16* wst = lw + srow * LDH + scol;
    _Float16* xst = lx + srow * LDH + scol;

    // frag read pointers: A row = wm+(lane&15) (+16), B col-row = wn+(lane&15);
    // k = (lane>>4)*8 + j (+32 for second K32 substep)
    const _Float16* ap = lx + (wm + (lane & 15)) * LDH + (lane >> 4) * 8;
    const _Float16* bp = lw + (wn + (lane & 15)) * LDH + (lane >> 4) * 8;

    f32x4 acc0 = {0.f, 0.f, 0.f, 0.f};
    f32x4 acc1 = {0.f, 0.f, 0.f, 0.f};

    // prologue: load first K-slab into regs
    float4 cw0 = *(const float4*)(wp);
    float4 cw1 = *(const float4*)(wp + 4);
    float4 cx0 = *(const float4*)(xp);
    float4 cx1 = *(const float4*)(xp + 4);

    for (int k0 = 0; k0 < K; k0 += BK) {
        // issue next slab's loads FIRST -> full-iteration latency window
        const int kn = k0 + BK;
        float4 nw0, nw1, nx0, nx1;
        if (kn < K) {
            nw0 = *(const float4*)(wp + kn);
            nw1 = *(const float4*)(wp + kn + 4);
            nx0 = *(const float4*)(xp + kn);
            nx1 = *(const float4*)(xp + kn + 4);
        }

        // convert current slab fp32 -> fp16 (exact) and stage
        *(half8*)wst = cvt8(cw0, cw1);
        *(half8*)xst = cvt8(cx0, cx1);
        __syncthreads();

        half8 a0 = *(const half8*)(ap);
        half8 a1 = *(const half8*)(ap + 16 * LDH);
        half8 a2 = *(const half8*)(ap + 32);
        half8 a3 = *(const half8*)(ap + 16 * LDH + 32);
        half8 b0 = *(const half8*)(bp);
        half8 b1 = *(const half8*)(bp + 32);

        acc0 = __builtin_amdgcn_mfma_f32_16x16x32_f16(a0, b0, acc0, 0, 0, 0);
        acc1 = __builtin_amdgcn_mfma_f32_16x16x32_f16(a1, b0, acc1, 0, 0, 0);
        acc0 = __builtin_amdgcn_mfma_f32_16x16x32_f16(a2, b1, acc0, 0, 0, 0);
        acc1 = __builtin_amdgcn_mfma_f32_16x16x32_f16(a3, b1, acc1, 0, 0, 0);

        if (kn < K) { cw0 = nw0; cw1 = nw1; cx0 = nx0; cx1 = nx1; }
        __syncthreads();   // protect LDS before next iteration's stores
    }

    // epilogue: C/D layout col = lane&15, row = (lane>>4)*4 + reg  [m89/m91]
    // mimic reference rounding: fp16(acc*scale), then fp16(+bias), store as fp32
    const int orow = bm + wm + ((lane >> 4) << 2);
    const int ocol = bn + wn + (lane & 15);
    const float sc = S[ocol];
    const float bi = Bi[ocol];
    #pragma unroll
    for (int r = 0; r < 4; ++r) {
        _Float16 h0 = (_Float16)(acc0[r] * sc);
        _Float16 h1 = (_Float16)((float)h0 + bi);
        O[(size_t)(orow + r) * N + ocol] = (float)h1;
        _Float16 g0 = (_Float16)(acc1[r] * sc);
        _Float16 g1 = (_Float16)((float)g0 + bi);
        O[(size_t)(orow + 16 + r) * N + ocol] = (float)g1;
    }
}

extern "C" void kernel_launch(void* const* d_in, const int* in_sizes, int n_in,
                              void* d_out, int out_size, void* d_ws, size_t ws_size,
                              hipStream_t stream) {
    const float* x  = (const float*)d_in[0];
    const float* w  = (const float*)d_in[1];
    const float* s  = (const float*)d_in[2];
    const float* bi = (const float*)d_in[3];
    float* o = (float*)d_out;

    fp6lin_kernel<<<dim3(256), dim3(512), 0, stream>>>(x, w, s, bi, o);
}